// Round 2
// baseline (600.856 us; speedup 1.0000x reference)
//
#include <hip/hip_runtime.h>

typedef unsigned short u16b;
typedef __attribute__((ext_vector_type(8))) short short8;
typedef __attribute__((ext_vector_type(4))) float float4v;

#define DEV __device__ __forceinline__

DEV float b2f(u16b u){ union{unsigned int i; float f;} x; x.i=((unsigned int)u)<<16; return x.f; }
DEV u16b f2b(float f){ union{float f; unsigned int i;} x; x.f=f;
  return (u16b)((x.i + 0x7fffu + ((x.i>>16)&1u))>>16); }

// Load 8 consecutive elements as bf16, converting from f32 if flag==0.
DEV short8 ld8(const void* base, size_t idx, int f){
  if (f) return *(const short8*)((const u16b*)base + idx);
  const float* p = (const float*)base + idx;
  float4v a = *(const float4v*)p;
  float4v b = *(const float4v*)(p+4);
  short8 r;
  r[0]=(short)f2b(a[0]); r[1]=(short)f2b(a[1]); r[2]=(short)f2b(a[2]); r[3]=(short)f2b(a[3]);
  r[4]=(short)f2b(b[0]); r[5]=(short)f2b(b[1]); r[6]=(short)f2b(b[2]); r[7]=(short)f2b(b[3]);
  return r;
}

// ---------------------------------------------------------------------------
// Dtype sniffer: decides whether inputs are bf16 (flag=1) or f32 (flag=0).
// Samples even u16 indices of qk. bf16 N(0,1) data: exponent in [100,134],
// nonzero -> ~100% plausible. f32 data: even u16 = low mantissa half ->
// uniform garbage (~14% plausible) or exact zero (bf16-rounded f32) -> f32.
// ---------------------------------------------------------------------------
__global__ void sniff_k(const void* __restrict__ qk, int* __restrict__ flag){
  const u16b* u = (const u16b*)qk;
  int t = threadIdx.x;
  u16b x = u[(size_t)2*t*257];
  int e = (x>>7)&0xFF;
  int ok = (e>=100 && e<=134 && (x&0x7FFF)!=0) ? 1 : 0;
  unsigned long long b = __ballot(ok);
  __shared__ int cnt[4];
  if ((t&63)==0) cnt[t>>6] = __popcll(b);
  __syncthreads();
  if (t==0) *flag = (cnt[0]+cnt[1]+cnt[2]+cnt[3] >= 128) ? 1 : 0;
}

// ---------------------------------------------------------------------------
// Ingest: convert 9 small tensors (weights/biases/masks) to canonical bf16.
// ---------------------------------------------------------------------------
struct IngestArgs {
  const void* src[9];
  int n[9];
  int off[9];
};

__global__ __launch_bounds__(256)
void ingest_k(IngestArgs a, u16b* __restrict__ dst, const int* __restrict__ flag){
  const int f = *flag;
  const int stride = gridDim.x*blockDim.x;
#pragma unroll
  for (int t=0;t<9;t++){
    const void* s = a.src[t];
    int n = a.n[t], o = a.off[t];
    for (int i = blockIdx.x*blockDim.x + threadIdx.x; i < n; i += stride){
      float v = f ? b2f(((const u16b*)s)[i]) : ((const float*)s)[i];
      dst[o + i] = f2b(v);
    }
  }
}

// ---------------------------------------------------------------------------
// Transpose+convert: in [R][C] (f32 or bf16) -> out [C][R] bf16, batch = z.
// ---------------------------------------------------------------------------
__global__ __launch_bounds__(256,4)
void transpose_k(const void* __restrict__ in, u16b* __restrict__ out,
                 const int* __restrict__ flag, int R, int C)
{
  __shared__ u16b tile[64][72];              // +8 pad
  const int f = *flag;
  const int c0 = blockIdx.x*64;
  const int r0 = blockIdx.y*64;
  const size_t base = (size_t)blockIdx.z * (size_t)R * (size_t)C;
  const int tid = threadIdx.x;
#pragma unroll
  for (int i=0;i<2;i++){
    int idx = i*256+tid;
    int rr = idx>>3;            // 0..63 row
    int cc = (idx&7)*8;         // col chunk
    *(short8*)&tile[rr][cc] = ld8(in, base + (size_t)(r0+rr)*C + c0 + cc, f);
  }
  __syncthreads();
#pragma unroll
  for (int i=0;i<2;i++){
    int idx = i*256+tid;
    int cc = idx>>3;            // col (s) local 0..63
    int rr = (idx&7)*8;         // row (d) chunk
    short8 v;
#pragma unroll
    for (int j=0;j<8;j++) v[j] = (short)tile[rr+j][cc];
    *(short8*)&out[base + (size_t)(c0+cc)*R + r0 + rr] = v;
  }
}

// ---------------------------------------------------------------------------
// GEMM: C[m][n] = sum_k A[m*K+k]*B[n*K+k]   (both operands k-major, bf16)
// MODE 0: += bias[n], store C[m*N+n]            (Q/K proj, C=[bs][e])
// MODE 1: += bias[m], store C[m*N+n]            (V proj,   C=[e][bs])
// MODE 2: += bias[m], *= mask[n], remap to out[b][m][s], n=b*4096+s;
//         store f32 or bf16 per flag.
// ---------------------------------------------------------------------------
template<int MODE>
__global__ __launch_bounds__(256,2)
void gemm_kt(const u16b* __restrict__ A, const u16b* __restrict__ B,
             void* __restrict__ Cv, const u16b* __restrict__ bias,
             const u16b* __restrict__ mask, const int* __restrict__ flag,
             int M, int N, int K)
{
  __shared__ u16b a_sh[128][40];   // 32 k + 8 pad
  __shared__ u16b b_sh[128][40];
  const int f = (MODE==2) ? *flag : 0;
  const int tid  = threadIdx.x;
  const int lane = tid & 63;
  const int wv   = tid >> 6;
  const int wm   = (wv>>1)*64, wn = (wv&1)*64;
  const int q    = lane>>4, ln = lane&15;
  const int m0   = blockIdx.y*128, n0 = blockIdx.x*128;

  float4v acc[4][4];
#pragma unroll
  for (int i=0;i<4;i++)
#pragma unroll
    for (int j=0;j<4;j++) acc[i][j] = float4v{0.f,0.f,0.f,0.f};

  for (int k0=0; k0<K; k0+=32){
    __syncthreads();
#pragma unroll
    for (int i=0;i<2;i++){
      int idx=i*256+tid, row=idx>>2, ch=(idx&3)*8;
      *(short8*)&a_sh[row][ch] = *(const short8*)&A[(size_t)(m0+row)*K + k0 + ch];
      *(short8*)&b_sh[row][ch] = *(const short8*)&B[(size_t)(n0+row)*K + k0 + ch];
    }
    __syncthreads();
    short8 af[4], bfr[4];
#pragma unroll
    for (int mt=0;mt<4;mt++) af[mt]  = *(const short8*)&a_sh[wm+mt*16+ln][q*8];
#pragma unroll
    for (int nt=0;nt<4;nt++) bfr[nt] = *(const short8*)&b_sh[wn+nt*16+ln][q*8];
#pragma unroll
    for (int mt=0;mt<4;mt++)
#pragma unroll
      for (int nt=0;nt<4;nt++)
        acc[mt][nt] = __builtin_amdgcn_mfma_f32_16x16x32_bf16(
            af[mt], bfr[nt], acc[mt][nt], 0,0,0);
  }

#pragma unroll
  for (int mt=0;mt<4;mt++)
#pragma unroll
    for (int nt=0;nt<4;nt++)
#pragma unroll
      for (int r=0;r<4;r++){
        int gm = m0 + wm + mt*16 + q*4 + r;
        int gn = n0 + wn + nt*16 + ln;
        float v = acc[mt][nt][r];
        if (MODE==0) v += b2f(bias[gn]);
        else         v += b2f(bias[gm]);
        if (MODE==2){
          v *= b2f(mask[gn]);
          size_t oidx = ((size_t)(gn>>12)*1024 + gm)*4096 + (gn&4095);
          if (f) ((u16b*)Cv)[oidx] = f2b(v);
          else   ((float*)Cv)[oidx] = v;
        } else {
          ((u16b*)Cv)[(size_t)gm*N + gn] = f2b(v);
        }
      }
}

// ---------------------------------------------------------------------------
// Windowed attention per (window w, head h). 4 waves, 32 q-rows each.
// QT/KT: [32768][512] (s-major). V2: [512][32768] (e-major). GT aliases KT
// (block-private tile; all K reads precede the barrier, GT writes follow).
// ---------------------------------------------------------------------------
__global__ __launch_bounds__(256,2)
void attn_k(const u16b* __restrict__ QT, const u16b* __restrict__ KT,
            const u16b* __restrict__ V2, const u16b* __restrict__ mask,
            u16b* __restrict__ GT)
{
  __shared__ u16b v_sh[64][136];
  __shared__ u16b p_sh[4][32][136];
  const int bid = blockIdx.x;
  const int w = bid>>3, h = bid&7;
  const int tid = threadIdx.x, lane = tid&63, wv = tid>>6;
  const int q = lane>>4, ln = lane&15;
  const size_t cb = (size_t)w*128;

#pragma unroll
  for (int i=0;i<4;i++){
    int idx=i*256+tid, row=idx>>4, ch=(idx&15)*8;
    *(short8*)&v_sh[row][ch] =
        *(const short8*)&V2[(size_t)(h*64+row)*32768 + cb + ch];
  }

  short8 qf[2][2], kf[8][2];
#pragma unroll
  for (int mt=0;mt<2;mt++)
#pragma unroll
    for (int ks=0;ks<2;ks++)
      qf[mt][ks] = *(const short8*)&QT[(cb + wv*32 + mt*16 + ln)*512 + h*64 + ks*32 + q*8];
#pragma unroll
  for (int nt=0;nt<8;nt++)
#pragma unroll
    for (int ks=0;ks<2;ks++)
      kf[nt][ks] = *(const short8*)&KT[(cb + nt*16 + ln)*512 + h*64 + ks*32 + q*8];

  float4v sa[2][8];
#pragma unroll
  for (int mt=0;mt<2;mt++)
#pragma unroll
    for (int nt=0;nt<8;nt++) sa[mt][nt] = float4v{0.f,0.f,0.f,0.f};
#pragma unroll
  for (int ks=0;ks<2;ks++)
#pragma unroll
    for (int mt=0;mt<2;mt++)
#pragma unroll
      for (int nt=0;nt<8;nt++)
        sa[mt][nt] = __builtin_amdgcn_mfma_f32_16x16x32_bf16(
            qf[mt][ks], kf[nt][ks], sa[mt][nt], 0,0,0);

  float mk[8];
#pragma unroll
  for (int nt=0;nt<8;nt++) mk[nt] = b2f(mask[cb + nt*16 + ln]);
#pragma unroll
  for (int mt=0;mt<2;mt++)
#pragma unroll
    for (int nt=0;nt<8;nt++)
#pragma unroll
      for (int r=0;r<4;r++){
        float s = sa[mt][nt][r]*0.125f;          // /sqrt(dh=64)
        sa[mt][nt][r] = (mk[nt] > 0.0f) ? s : -1e9f;
      }

  float mrow[2][4], lrow[2][4];
#pragma unroll
  for (int mt=0;mt<2;mt++)
#pragma unroll
    for (int r=0;r<4;r++){
      float m = -3e38f;
#pragma unroll
      for (int nt=0;nt<8;nt++) m = fmaxf(m, sa[mt][nt][r]);
#pragma unroll
      for (int d=1; d<16; d<<=1) m = fmaxf(m, __shfl_xor(m, d));
      mrow[mt][r] = m;
    }
#pragma unroll
  for (int mt=0;mt<2;mt++)
#pragma unroll
    for (int nt=0;nt<8;nt++)
#pragma unroll
      for (int r=0;r<4;r++)
        sa[mt][nt][r] = __expf(sa[mt][nt][r] - mrow[mt][r]);
#pragma unroll
  for (int mt=0;mt<2;mt++)
#pragma unroll
    for (int r=0;r<4;r++){
      float l = 0.f;
#pragma unroll
      for (int nt=0;nt<8;nt++) l += sa[mt][nt][r];
#pragma unroll
      for (int d=1; d<16; d<<=1) l += __shfl_xor(l, d);
      lrow[mt][r] = l;
    }

#pragma unroll
  for (int mt=0;mt<2;mt++)
#pragma unroll
    for (int nt=0;nt<8;nt++)
#pragma unroll
      for (int r=0;r<4;r++)
        p_sh[wv][mt*16 + q*4 + r][nt*16 + ln] = f2b(sa[mt][nt][r]);
  __syncthreads();   // covers v_sh staging, p_sh, and all KT(GT-alias) reads

  float4v oa[2][4];
#pragma unroll
  for (int mt=0;mt<2;mt++)
#pragma unroll
    for (int nt=0;nt<4;nt++) oa[mt][nt] = float4v{0.f,0.f,0.f,0.f};
#pragma unroll
  for (int ks=0;ks<4;ks++){
    short8 pf[2], vf[4];
#pragma unroll
    for (int mt=0;mt<2;mt++) pf[mt] = *(const short8*)&p_sh[wv][mt*16+ln][ks*32+q*8];
#pragma unroll
    for (int nt=0;nt<4;nt++) vf[nt] = *(const short8*)&v_sh[nt*16+ln][ks*32+q*8];
#pragma unroll
    for (int mt=0;mt<2;mt++)
#pragma unroll
      for (int nt=0;nt<4;nt++)
        oa[mt][nt] = __builtin_amdgcn_mfma_f32_16x16x32_bf16(
            pf[mt], vf[nt], oa[mt][nt], 0,0,0);
  }

#pragma unroll
  for (int mt=0;mt<2;mt++)
#pragma unroll
    for (int nt=0;nt<4;nt++)
#pragma unroll
      for (int r=0;r<4;r++){
        float x = oa[mt][nt][r] * (1.0f / lrow[mt][r]);
        float g = 0.5f * x * (1.0f + erff(x * 0.70710678118f));
        GT[(cb + wv*32 + mt*16 + q*4 + r)*512 + h*64 + nt*16 + ln] = f2b(g);
      }
}

// ---------------------------------------------------------------------------
extern "C" void kernel_launch(void* const* d_in, const int* in_sizes, int n_in,
                              void* d_out, int out_size, void* d_ws, size_t ws_size,
                              hipStream_t stream)
{
  const void* qk    = d_in[0];
  const void* v     = d_in[1];
  const void* masks = d_in[2];

  char* ws = (char*)d_ws;
  int*  flag  = (int*)ws;                          // [0,1KB)
  u16b* wbase = (u16b*)(ws + 1024);                // canonical bf16 weights
  // element offsets within wbase:
  const int OWQ=0, OWK=524288, OWV=1048576, OWO=1572864;
  const int OBQ=2097152, OBK=2097664, OBV=2098176, OBO=2098688, OMSK=2099712;

  u16b* Xt = (u16b*)d_out;                         // [32768][1024] bf16 (64MB)
  u16b* QT = (u16b*)(ws + ((size_t) 8<<20));       // [32768][512]  32MB
  u16b* KT = (u16b*)(ws + ((size_t)40<<20));       // [32768][512]  32MB (GT aliases)
  u16b* V2 = (u16b*)(ws + ((size_t)72<<20));       // [512][32768]  32MB
  u16b* GT = KT;

  sniff_k<<<1,256,0,stream>>>(qk, flag);

  IngestArgs ia;
  ia.src[0]=d_in[3]; ia.n[0]=524288; ia.off[0]=OWQ;   // Wq
  ia.src[1]=d_in[5]; ia.n[1]=524288; ia.off[1]=OWK;   // Wk
  ia.src[2]=d_in[7]; ia.n[2]=524288; ia.off[2]=OWV;   // Wv
  ia.src[3]=d_in[9]; ia.n[3]=524288; ia.off[3]=OWO;   // Wo
  ia.src[4]=d_in[4]; ia.n[4]=512;    ia.off[4]=OBQ;   // bq
  ia.src[5]=d_in[6]; ia.n[5]=512;    ia.off[5]=OBK;   // bk
  ia.src[6]=d_in[8]; ia.n[6]=512;    ia.off[6]=OBV;   // bv
  ia.src[7]=d_in[10];ia.n[7]=1024;   ia.off[7]=OBO;   // bo
  ia.src[8]=masks;   ia.n[8]=32768;  ia.off[8]=OMSK;  // masks
  ingest_k<<<1024,256,0,stream>>>(ia, wbase, flag);

  dim3 tg(64,16,8);
  transpose_k<<<tg,256,0,stream>>>(qk, Xt, flag, 1024, 4096);
  gemm_kt<0><<<dim3(4,256),256,0,stream>>>(Xt, wbase+OWQ, QT, wbase+OBQ, nullptr, flag, 32768, 512, 1024);
  gemm_kt<0><<<dim3(4,256),256,0,stream>>>(Xt, wbase+OWK, KT, wbase+OBK, nullptr, flag, 32768, 512, 1024);
  transpose_k<<<tg,256,0,stream>>>(v, Xt, flag, 1024, 4096);
  gemm_kt<1><<<dim3(256,4),256,0,stream>>>(wbase+OWV, Xt, V2, wbase+OBV, nullptr, flag, 512, 32768, 1024);
  attn_k<<<2048,256,0,stream>>>(QT, KT, V2, wbase+OMSK, GT);
  gemm_kt<2><<<dim3(256,8),256,0,stream>>>(wbase+OWO, GT, d_out, wbase+OBO, wbase+OMSK, flag, 1024, 32768, 512);
}

// Round 3
// 591.236 us; speedup vs baseline: 1.0163x; 1.0163x over previous
//
#include <hip/hip_runtime.h>

typedef unsigned short u16b;
typedef __attribute__((ext_vector_type(8))) short short8;
typedef __attribute__((ext_vector_type(4))) float float4v;

#define DEV __device__ __forceinline__

DEV float b2f(u16b u){ union{unsigned int i; float f;} x; x.i=((unsigned int)u)<<16; return x.f; }
DEV u16b f2b(float f){ union{float f; unsigned int i;} x; x.f=f;
  return (u16b)((x.i + 0x7fffu + ((x.i>>16)&1u))>>16); }

// async global->LDS DMA, 16B per lane; lds must be the wave-uniform base.
DEV void g2l16(const u16b* g, u16b* l){
  __builtin_amdgcn_global_load_lds(
      (const __attribute__((address_space(1))) void*)g,
      (__attribute__((address_space(3))) void*)l, 16, 0, 0);
}

// Load 8 consecutive elements as bf16, converting from f32 if flag==0.
DEV short8 ld8(const void* base, size_t idx, int f){
  if (f) return *(const short8*)((const u16b*)base + idx);
  const float* p = (const float*)base + idx;
  float4v a = *(const float4v*)p;
  float4v b = *(const float4v*)(p+4);
  short8 r;
  r[0]=(short)f2b(a[0]); r[1]=(short)f2b(a[1]); r[2]=(short)f2b(a[2]); r[3]=(short)f2b(a[3]);
  r[4]=(short)f2b(b[0]); r[5]=(short)f2b(b[1]); r[6]=(short)f2b(b[2]); r[7]=(short)f2b(b[3]);
  return r;
}

// ---------------------------------------------------------------------------
// Dtype sniffer: bf16 (flag=1) vs f32 (flag=0). See R1 notes.
// ---------------------------------------------------------------------------
__global__ void sniff_k(const void* __restrict__ qk, int* __restrict__ flag){
  const u16b* u = (const u16b*)qk;
  int t = threadIdx.x;
  u16b x = u[(size_t)2*t*257];
  int e = (x>>7)&0xFF;
  int ok = (e>=100 && e<=134 && (x&0x7FFF)!=0) ? 1 : 0;
  unsigned long long b = __ballot(ok);
  __shared__ int cnt[4];
  if ((t&63)==0) cnt[t>>6] = __popcll(b);
  __syncthreads();
  if (t==0) *flag = (cnt[0]+cnt[1]+cnt[2]+cnt[3] >= 128) ? 1 : 0;
}

// ---------------------------------------------------------------------------
// Ingest: convert 9 small tensors (weights/biases/masks) to canonical bf16.
// ---------------------------------------------------------------------------
struct IngestArgs {
  const void* src[9];
  int n[9];
  int off[9];
};

__global__ __launch_bounds__(256)
void ingest_k(IngestArgs a, u16b* __restrict__ dst, const int* __restrict__ flag){
  const int f = *flag;
  const int stride = gridDim.x*blockDim.x;
#pragma unroll
  for (int t=0;t<9;t++){
    const void* s = a.src[t];
    int n = a.n[t], o = a.off[t];
    for (int i = blockIdx.x*blockDim.x + threadIdx.x; i < n; i += stride){
      float v = f ? b2f(((const u16b*)s)[i]) : ((const float*)s)[i];
      dst[o + i] = f2b(v);
    }
  }
}

// ---------------------------------------------------------------------------
// Transpose+convert both inputs in one launch:
//  z<8 : qk [1024][4096] batch z   -> Xtq [4096][1024] bf16
//  z>=8: v  [1024][4096] batch z-8 -> Xtv [4096][1024] bf16
// ---------------------------------------------------------------------------
__global__ __launch_bounds__(256,4)
void transpose2_k(const void* __restrict__ qk, const void* __restrict__ vv,
                  u16b* __restrict__ outq, u16b* __restrict__ outv,
                  const int* __restrict__ flag)
{
  __shared__ u16b tile[64][72];              // +8 pad
  const int f = *flag;
  const int R = 1024, C = 4096;
  const int z = blockIdx.z;
  const void* in = (z<8) ? qk : vv;
  u16b* out = (z<8) ? outq : outv;
  const int zz = z&7;
  const int c0 = blockIdx.x*64;
  const int r0 = blockIdx.y*64;
  const size_t base = (size_t)zz * (size_t)R * (size_t)C;
  const int tid = threadIdx.x;
#pragma unroll
  for (int i=0;i<2;i++){
    int idx = i*256+tid;
    int rr = idx>>3;
    int cc = (idx&7)*8;
    *(short8*)&tile[rr][cc] = ld8(in, base + (size_t)(r0+rr)*C + c0 + cc, f);
  }
  __syncthreads();
#pragma unroll
  for (int i=0;i<2;i++){
    int idx = i*256+tid;
    int cc = idx>>3;
    int rr = (idx&7)*8;
    short8 v;
#pragma unroll
    for (int j=0;j<8;j++) v[j] = (short)tile[rr+j][cc];
    *(short8*)&out[base + (size_t)(c0+cc)*R + r0 + rr] = v;
  }
}

// ---------------------------------------------------------------------------
// GEMM: C[m][n] = sum_k A[m*K+k]*B[n*K+k]  (both k-major bf16), m97-style:
// global_load_lds dwordx4 staging into XOR-swizzled unpadded LDS.
// LDS chunk index for (row r, kchunk kc): L = r*4 + (kc ^ ((r>>1)&3)).
//   -> staging is lane-contiguous (DMA constraint), fragment ds_read_b128
//      lands 2 lanes/bank-group (free).
// MODE 1: += bias[m], store C[m*N+n]                   (V proj, C=[e][bs])
// MODE 2: += bias[m], *= mask[n], remap out[b][m][s], f32-or-bf16 by flag
// MODE 3: += bias[n]; n<512 -> QT[m][n], else KT[m][n-512] (KT = QT+16M elems)
// ---------------------------------------------------------------------------
template<int MODE>
__global__ __launch_bounds__(256,2)
void gemm_kt(const u16b* __restrict__ A, const u16b* __restrict__ B,
             void* __restrict__ Cv, const u16b* __restrict__ bias,
             const u16b* __restrict__ mask, const int* __restrict__ flag,
             int M, int N, int K)
{
  __shared__ __align__(16) u16b a_sh[4096];   // 128 rows x 32 k, swizzled, 8KB
  __shared__ __align__(16) u16b b_sh[4096];
  const int f = (MODE==2) ? *flag : 0;
  const int tid  = threadIdx.x;
  const int lane = tid & 63;
  const int wv   = tid >> 6;
  const int wm   = (wv>>1)*64, wn = (wv&1)*64;
  const int q    = lane>>4, ln = lane&15;
  const int m0   = blockIdx.y*128, n0 = blockIdx.x*128;

  // staging constants: wave wv DMAs 1KB chunk-groups c=wv and c=wv+4
  const int L0 = wv*64 + lane;
  const int r0s = L0>>2;
  const int kc0 = (L0&3) ^ ((r0s>>1)&3);
  const int L1 = (wv+4)*64 + lane;
  const int r1s = L1>>2;
  const int kc1 = (L1&3) ^ ((r1s>>1)&3);
  const size_t ga0 = (size_t)(m0+r0s)*K + (kc0<<3);
  const size_t ga1 = (size_t)(m0+r1s)*K + (kc1<<3);
  const size_t gb0 = (size_t)(n0+r0s)*K + (kc0<<3);
  const size_t gb1 = (size_t)(n0+r1s)*K + (kc1<<3);

  // fragment read offsets (elements): row*32 + (q^((ln>>1)&3))*8, + mt*512
  const int sw  = (q ^ ((ln>>1)&3))<<3;
  const int aoff = (wm+ln)*32 + sw;
  const int boff = (wn+ln)*32 + sw;

  float4v acc[4][4];
#pragma unroll
  for (int i=0;i<4;i++)
#pragma unroll
    for (int j=0;j<4;j++) acc[i][j] = float4v{0.f,0.f,0.f,0.f};

  for (int k0=0; k0<K; k0+=32){
    __syncthreads();
    g2l16(&A[ga0 + k0], &a_sh[wv*512]);
    g2l16(&A[ga1 + k0], &a_sh[(wv+4)*512]);
    g2l16(&B[gb0 + k0], &b_sh[wv*512]);
    g2l16(&B[gb1 + k0], &b_sh[(wv+4)*512]);
    asm volatile("s_waitcnt vmcnt(0)" ::: "memory");
    __syncthreads();
    short8 af[4], bfr[4];
#pragma unroll
    for (int mt=0;mt<4;mt++) af[mt]  = *(const short8*)&a_sh[aoff + mt*512];
#pragma unroll
    for (int nt=0;nt<4;nt++) bfr[nt] = *(const short8*)&b_sh[boff + nt*512];
#pragma unroll
    for (int mt=0;mt<4;mt++)
#pragma unroll
      for (int nt=0;nt<4;nt++)
        acc[mt][nt] = __builtin_amdgcn_mfma_f32_16x16x32_bf16(
            af[mt], bfr[nt], acc[mt][nt], 0,0,0);
  }

#pragma unroll
  for (int mt=0;mt<4;mt++)
#pragma unroll
    for (int nt=0;nt<4;nt++)
#pragma unroll
      for (int r=0;r<4;r++){
        int gm = m0 + wm + mt*16 + q*4 + r;
        int gn = n0 + wn + nt*16 + ln;
        float v = acc[mt][nt][r];
        if (MODE==3) v += b2f(bias[gn]);
        else         v += b2f(bias[gm]);
        if (MODE==2){
          v *= b2f(mask[gn]);
          size_t oidx = ((size_t)(gn>>12)*1024 + gm)*4096 + (gn&4095);
          if (f) ((u16b*)Cv)[oidx] = f2b(v);
          else   ((float*)Cv)[oidx] = v;
        } else if (MODE==3){
          u16b* dst = (u16b*)Cv + ((size_t)(gn>>9)<<24);  // +16M elems if K-half
          dst[(size_t)gm*512 + (gn&511)] = f2b(v);
        } else {
          ((u16b*)Cv)[(size_t)gm*N + gn] = f2b(v);
        }
      }
}

// ---------------------------------------------------------------------------
// Windowed attention per (window w, head h). 4 waves, 32 q-rows each.
// QT/KT: [32768][512] (s-major). V2: [512][32768] (e-major). GT aliases KT
// (block-private tile; all K reads precede the barrier, GT writes follow).
// ---------------------------------------------------------------------------
__global__ __launch_bounds__(256,2)
void attn_k(const u16b* __restrict__ QT, const u16b* __restrict__ KT,
            const u16b* __restrict__ V2, const u16b* __restrict__ mask,
            u16b* __restrict__ GT)
{
  __shared__ u16b v_sh[64][136];
  __shared__ u16b p_sh[4][32][136];
  const int bid = blockIdx.x;
  const int w = bid>>3, h = bid&7;
  const int tid = threadIdx.x, lane = tid&63, wv = tid>>6;
  const int q = lane>>4, ln = lane&15;
  const size_t cb = (size_t)w*128;

#pragma unroll
  for (int i=0;i<4;i++){
    int idx=i*256+tid, row=idx>>4, ch=(idx&15)*8;
    *(short8*)&v_sh[row][ch] =
        *(const short8*)&V2[(size_t)(h*64+row)*32768 + cb + ch];
  }

  short8 qf[2][2], kf[8][2];
#pragma unroll
  for (int mt=0;mt<2;mt++)
#pragma unroll
    for (int ks=0;ks<2;ks++)
      qf[mt][ks] = *(const short8*)&QT[(cb + wv*32 + mt*16 + ln)*512 + h*64 + ks*32 + q*8];
#pragma unroll
  for (int nt=0;nt<8;nt++)
#pragma unroll
    for (int ks=0;ks<2;ks++)
      kf[nt][ks] = *(const short8*)&KT[(cb + nt*16 + ln)*512 + h*64 + ks*32 + q*8];

  float4v sa[2][8];
#pragma unroll
  for (int mt=0;mt<2;mt++)
#pragma unroll
    for (int nt=0;nt<8;nt++) sa[mt][nt] = float4v{0.f,0.f,0.f,0.f};
#pragma unroll
  for (int ks=0;ks<2;ks++)
#pragma unroll
    for (int mt=0;mt<2;mt++)
#pragma unroll
      for (int nt=0;nt<8;nt++)
        sa[mt][nt] = __builtin_amdgcn_mfma_f32_16x16x32_bf16(
            qf[mt][ks], kf[nt][ks], sa[mt][nt], 0,0,0);

  float mk[8];
#pragma unroll
  for (int nt=0;nt<8;nt++) mk[nt] = b2f(mask[cb + nt*16 + ln]);
#pragma unroll
  for (int mt=0;mt<2;mt++)
#pragma unroll
    for (int nt=0;nt<8;nt++)
#pragma unroll
      for (int r=0;r<4;r++){
        float s = sa[mt][nt][r]*0.125f;          // /sqrt(dh=64)
        sa[mt][nt][r] = (mk[nt] > 0.0f) ? s : -1e9f;
      }

  float mrow[2][4], lrow[2][4];
#pragma unroll
  for (int mt=0;mt<2;mt++)
#pragma unroll
    for (int r=0;r<4;r++){
      float m = -3e38f;
#pragma unroll
      for (int nt=0;nt<8;nt++) m = fmaxf(m, sa[mt][nt][r]);
#pragma unroll
      for (int d=1; d<16; d<<=1) m = fmaxf(m, __shfl_xor(m, d));
      mrow[mt][r] = m;
    }
#pragma unroll
  for (int mt=0;mt<2;mt++)
#pragma unroll
    for (int nt=0;nt<8;nt++)
#pragma unroll
      for (int r=0;r<4;r++)
        sa[mt][nt][r] = __expf(sa[mt][nt][r] - mrow[mt][r]);
#pragma unroll
  for (int mt=0;mt<2;mt++)
#pragma unroll
    for (int r=0;r<4;r++){
      float l = 0.f;
#pragma unroll
      for (int nt=0;nt<8;nt++) l += sa[mt][nt][r];
#pragma unroll
      for (int d=1; d<16; d<<=1) l += __shfl_xor(l, d);
      lrow[mt][r] = l;
    }

#pragma unroll
  for (int mt=0;mt<2;mt++)
#pragma unroll
    for (int nt=0;nt<8;nt++)
#pragma unroll
      for (int r=0;r<4;r++)
        p_sh[wv][mt*16 + q*4 + r][nt*16 + ln] = f2b(sa[mt][nt][r]);
  __syncthreads();   // covers v_sh staging, p_sh, and all KT(GT-alias) reads

  float4v oa[2][4];
#pragma unroll
  for (int mt=0;mt<2;mt++)
#pragma unroll
    for (int nt=0;nt<4;nt++) oa[mt][nt] = float4v{0.f,0.f,0.f,0.f};
#pragma unroll
  for (int ks=0;ks<4;ks++){
    short8 pf[2], vf[4];
#pragma unroll
    for (int mt=0;mt<2;mt++) pf[mt] = *(const short8*)&p_sh[wv][mt*16+ln][ks*32+q*8];
#pragma unroll
    for (int nt=0;nt<4;nt++) vf[nt] = *(const short8*)&v_sh[nt*16+ln][ks*32+q*8];
#pragma unroll
    for (int mt=0;mt<2;mt++)
#pragma unroll
      for (int nt=0;nt<4;nt++)
        oa[mt][nt] = __builtin_amdgcn_mfma_f32_16x16x32_bf16(
            pf[mt], vf[nt], oa[mt][nt], 0,0,0);
  }

#pragma unroll
  for (int mt=0;mt<2;mt++)
#pragma unroll
    for (int nt=0;nt<4;nt++)
#pragma unroll
      for (int r=0;r<4;r++){
        float x = oa[mt][nt][r] * (1.0f / lrow[mt][r]);
        float g = 0.5f * x * (1.0f + erff(x * 0.70710678118f));
        GT[(cb + wv*32 + mt*16 + q*4 + r)*512 + h*64 + nt*16 + ln] = f2b(g);
      }
}

// ---------------------------------------------------------------------------
extern "C" void kernel_launch(void* const* d_in, const int* in_sizes, int n_in,
                              void* d_out, int out_size, void* d_ws, size_t ws_size,
                              hipStream_t stream)
{
  const void* qk    = d_in[0];
  const void* v     = d_in[1];
  const void* masks = d_in[2];

  char* ws = (char*)d_ws;
  int*  flag  = (int*)ws;                          // [0,1KB)
  u16b* wbase = (u16b*)(ws + 1024);                // canonical bf16 weights
  const int OWQ=0, OWK=524288, OWV=1048576, OWO=1572864;
  const int OBQ=2097152, OBK=2097664, OBV=2098176, OBO=2098688, OMSK=2099712;

  u16b* QT  = (u16b*)(ws + ((size_t)  8<<20));     // [32768][512] 32MB
  u16b* KT  = (u16b*)(ws + ((size_t) 40<<20));     // [32768][512] 32MB (=QT+16M)
  u16b* V2  = (u16b*)(ws + ((size_t) 72<<20));     // [512][32768] 32MB
  u16b* Xtq = (u16b*)(ws + ((size_t)104<<20));     // [32768][1024] 64MB
  u16b* Xtv = (u16b*)(ws + ((size_t)168<<20));     // [32768][1024] 64MB
  u16b* GT  = KT;

  sniff_k<<<1,256,0,stream>>>(qk, flag);

  IngestArgs ia;
  ia.src[0]=d_in[3]; ia.n[0]=524288; ia.off[0]=OWQ;   // Wq
  ia.src[1]=d_in[5]; ia.n[1]=524288; ia.off[1]=OWK;   // Wk
  ia.src[2]=d_in[7]; ia.n[2]=524288; ia.off[2]=OWV;   // Wv
  ia.src[3]=d_in[9]; ia.n[3]=524288; ia.off[3]=OWO;   // Wo
  ia.src[4]=d_in[4]; ia.n[4]=512;    ia.off[4]=OBQ;   // bq
  ia.src[5]=d_in[6]; ia.n[5]=512;    ia.off[5]=OBK;   // bk  (adjacent to bq)
  ia.src[6]=d_in[8]; ia.n[6]=512;    ia.off[6]=OBV;   // bv
  ia.src[7]=d_in[10];ia.n[7]=1024;   ia.off[7]=OBO;   // bo
  ia.src[8]=masks;   ia.n[8]=32768;  ia.off[8]=OMSK;  // masks
  ingest_k<<<1024,256,0,stream>>>(ia, wbase, flag);

  transpose2_k<<<dim3(64,16,16),256,0,stream>>>(qk, v, Xtq, Xtv, flag);
  // fused Q+K projection: B rows = [Wq ; Wk] (contiguous in wbase)
  gemm_kt<3><<<dim3(8,256),256,0,stream>>>(Xtq, wbase+OWQ, QT, wbase+OBQ, nullptr, flag, 32768, 1024, 1024);
  gemm_kt<1><<<dim3(256,4),256,0,stream>>>(wbase+OWV, Xtv, V2, wbase+OBV, nullptr, flag, 512, 32768, 1024);
  attn_k<<<2048,256,0,stream>>>(QT, KT, V2, wbase+OMSK, GT);
  gemm_kt<2><<<dim3(256,8),256,0,stream>>>(wbase+OWO, GT, d_out, wbase+OBO, wbase+OMSK, flag, 1024, 32768, 512);
}

// Round 4
// 589.571 us; speedup vs baseline: 1.0191x; 1.0028x over previous
//
#include <hip/hip_runtime.h>

typedef unsigned short u16b;
typedef __attribute__((ext_vector_type(8))) short short8;
typedef __attribute__((ext_vector_type(4))) float float4v;

#define DEV __device__ __forceinline__

DEV float b2f(u16b u){ union{unsigned int i; float f;} x; x.i=((unsigned int)u)<<16; return x.f; }
DEV u16b f2b(float f){ union{float f; unsigned int i;} x; x.f=f;
  return (u16b)((x.i + 0x7fffu + ((x.i>>16)&1u))>>16); }

// async global->LDS DMA, 16B per lane; lds must be the wave-uniform base.
DEV void g2l16(const u16b* g, u16b* l){
  __builtin_amdgcn_global_load_lds(
      (const __attribute__((address_space(1))) void*)g,
      (__attribute__((address_space(3))) void*)l, 16, 0, 0);
}

// Load 8 consecutive elements as bf16, converting from f32 if flag==0.
DEV short8 ld8(const void* base, size_t idx, int f){
  if (f) return *(const short8*)((const u16b*)base + idx);
  const float* p = (const float*)base + idx;
  float4v a = *(const float4v*)p;
  float4v b = *(const float4v*)(p+4);
  short8 r;
  r[0]=(short)f2b(a[0]); r[1]=(short)f2b(a[1]); r[2]=(short)f2b(a[2]); r[3]=(short)f2b(a[3]);
  r[4]=(short)f2b(b[0]); r[5]=(short)f2b(b[1]); r[6]=(short)f2b(b[2]); r[7]=(short)f2b(b[3]);
  return r;
}

// ---------------------------------------------------------------------------
// Dtype sniffer: bf16 (flag=1) vs f32 (flag=0). See R1 notes.
// ---------------------------------------------------------------------------
__global__ void sniff_k(const void* __restrict__ qk, int* __restrict__ flag){
  const u16b* u = (const u16b*)qk;
  int t = threadIdx.x;
  u16b x = u[(size_t)2*t*257];
  int e = (x>>7)&0xFF;
  int ok = (e>=100 && e<=134 && (x&0x7FFF)!=0) ? 1 : 0;
  unsigned long long b = __ballot(ok);
  __shared__ int cnt[4];
  if ((t&63)==0) cnt[t>>6] = __popcll(b);
  __syncthreads();
  if (t==0) *flag = (cnt[0]+cnt[1]+cnt[2]+cnt[3] >= 128) ? 1 : 0;
}

// ---------------------------------------------------------------------------
// Ingest: convert 9 small tensors (weights/biases/masks) to canonical bf16.
// ---------------------------------------------------------------------------
struct IngestArgs {
  const void* src[9];
  int n[9];
  int off[9];
};

__global__ __launch_bounds__(256)
void ingest_k(IngestArgs a, u16b* __restrict__ dst, const int* __restrict__ flag){
  const int f = *flag;
  const int stride = gridDim.x*blockDim.x;
#pragma unroll
  for (int t=0;t<9;t++){
    const void* s = a.src[t];
    int n = a.n[t], o = a.off[t];
    for (int i = blockIdx.x*blockDim.x + threadIdx.x; i < n; i += stride){
      float v = f ? b2f(((const u16b*)s)[i]) : ((const float*)s)[i];
      dst[o + i] = f2b(v);
    }
  }
}

// ---------------------------------------------------------------------------
// Transpose+convert both inputs, conflict-free u32-pair scheme:
//  z<8 : qk [1024][4096] batch z   -> Xtq [4096][1024] bf16
//  z>=8: v  [1024][4096] batch z-8 -> Xtv [4096][1024] bf16
// Pack (row 2r2, row 2r2+1) bf16 pair into one u32; LDS tile u32[32][65]
// (stride 65 = 1 mod 32 banks -> both phases <=2 lanes/bank, free).
// Read phase gathers 4 u32 = out[c][8r..8r+7], stored as one 16B uint4.
// ---------------------------------------------------------------------------
__global__ __launch_bounds__(256,4)
void transpose2_k(const void* __restrict__ qk, const void* __restrict__ vv,
                  u16b* __restrict__ outq, u16b* __restrict__ outv,
                  const int* __restrict__ flag)
{
  __shared__ unsigned int X[32*65 + 8];      // 8352 B
  const int f = *flag;
  const int R = 1024, C = 4096;
  const int z = blockIdx.z;
  const void* in = (z<8) ? qk : vv;
  u16b* out = (z<8) ? outq : outv;
  const int zz = z&7;
  const int c0 = blockIdx.x*64;
  const int r0 = blockIdx.y*64;
  const size_t base = (size_t)zz * (size_t)R * (size_t)C;
  const int t = threadIdx.x;
  const int r2 = t>>3, c8 = t&7;

  short8 va = ld8(in, base + (size_t)(r0 + 2*r2    )*C + c0 + c8*8, f);
  short8 vb = ld8(in, base + (size_t)(r0 + 2*r2 + 1)*C + c0 + c8*8, f);
#pragma unroll
  for (int k=0;k<8;k++){
    unsigned int w = (((unsigned int)(unsigned short)vb[k])<<16)
                   |  (unsigned int)(unsigned short)va[k];
    X[r2*65 + c8*8 + k] = w;
  }
  __syncthreads();
#pragma unroll
  for (int i=0;i<2;i++){
    int idx = i*256 + t;
    int c = idx>>3, rq = idx&7;
    unsigned int d0 = X[(4*rq+0)*65 + c];
    unsigned int d1 = X[(4*rq+1)*65 + c];
    unsigned int d2 = X[(4*rq+2)*65 + c];
    unsigned int d3 = X[(4*rq+3)*65 + c];
    uint4 o; o.x=d0; o.y=d1; o.z=d2; o.w=d3;
    *(uint4*)&out[base + (size_t)(c0+c)*R + r0 + 8*rq] = o;
  }
}

// ---------------------------------------------------------------------------
// GEMM: C[m][n] = sum_k A[m*K+k]*B[n*K+k]  (both k-major bf16), m97-style:
// global_load_lds dwordx4 staging into XOR-swizzled unpadded LDS.
// MODE 1: += bias[m], store C[m*N+n]                   (V proj, C=[e][bs])
// MODE 2: += bias[m], *= mask[n], remap out[b][m][s], f32-or-bf16 by flag
// MODE 3: += bias[n]; n<512 -> QT[m][n], else KT[m][n-512] (KT = QT+16M elems)
// ---------------------------------------------------------------------------
template<int MODE>
__global__ __launch_bounds__(256,2)
void gemm_kt(const u16b* __restrict__ A, const u16b* __restrict__ B,
             void* __restrict__ Cv, const u16b* __restrict__ bias,
             const u16b* __restrict__ mask, const int* __restrict__ flag,
             int M, int N, int K)
{
  __shared__ __align__(16) u16b a_sh[4096];   // 128 rows x 32 k, swizzled, 8KB
  __shared__ __align__(16) u16b b_sh[4096];
  const int f = (MODE==2) ? *flag : 0;
  const int tid  = threadIdx.x;
  const int lane = tid & 63;
  const int wv   = tid >> 6;
  const int wm   = (wv>>1)*64, wn = (wv&1)*64;
  const int q    = lane>>4, ln = lane&15;
  const int m0   = blockIdx.y*128, n0 = blockIdx.x*128;

  const int L0 = wv*64 + lane;
  const int r0s = L0>>2;
  const int kc0 = (L0&3) ^ ((r0s>>1)&3);
  const int L1 = (wv+4)*64 + lane;
  const int r1s = L1>>2;
  const int kc1 = (L1&3) ^ ((r1s>>1)&3);
  const size_t ga0 = (size_t)(m0+r0s)*K + (kc0<<3);
  const size_t ga1 = (size_t)(m0+r1s)*K + (kc1<<3);
  const size_t gb0 = (size_t)(n0+r0s)*K + (kc0<<3);
  const size_t gb1 = (size_t)(n0+r1s)*K + (kc1<<3);

  const int sw  = (q ^ ((ln>>1)&3))<<3;
  const int aoff = (wm+ln)*32 + sw;
  const int boff = (wn+ln)*32 + sw;

  float4v acc[4][4];
#pragma unroll
  for (int i=0;i<4;i++)
#pragma unroll
    for (int j=0;j<4;j++) acc[i][j] = float4v{0.f,0.f,0.f,0.f};

  for (int k0=0; k0<K; k0+=32){
    __syncthreads();
    g2l16(&A[ga0 + k0], &a_sh[wv*512]);
    g2l16(&A[ga1 + k0], &a_sh[(wv+4)*512]);
    g2l16(&B[gb0 + k0], &b_sh[wv*512]);
    g2l16(&B[gb1 + k0], &b_sh[(wv+4)*512]);
    asm volatile("s_waitcnt vmcnt(0)" ::: "memory");
    __syncthreads();
    short8 af[4], bfr[4];
#pragma unroll
    for (int mt=0;mt<4;mt++) af[mt]  = *(const short8*)&a_sh[aoff + mt*512];
#pragma unroll
    for (int nt=0;nt<4;nt++) bfr[nt] = *(const short8*)&b_sh[boff + nt*512];
#pragma unroll
    for (int mt=0;mt<4;mt++)
#pragma unroll
      for (int nt=0;nt<4;nt++)
        acc[mt][nt] = __builtin_amdgcn_mfma_f32_16x16x32_bf16(
            af[mt], bfr[nt], acc[mt][nt], 0,0,0);
  }

#pragma unroll
  for (int mt=0;mt<4;mt++)
#pragma unroll
    for (int nt=0;nt<4;nt++)
#pragma unroll
      for (int r=0;r<4;r++){
        int gm = m0 + wm + mt*16 + q*4 + r;
        int gn = n0 + wn + nt*16 + ln;
        float v = acc[mt][nt][r];
        if (MODE==3) v += b2f(bias[gn]);
        else         v += b2f(bias[gm]);
        if (MODE==2){
          v *= b2f(mask[gn]);
          size_t oidx = ((size_t)(gn>>12)*1024 + gm)*4096 + (gn&4095);
          if (f) ((u16b*)Cv)[oidx] = f2b(v);
          else   ((float*)Cv)[oidx] = v;
        } else if (MODE==3){
          u16b* dst = (u16b*)Cv + ((size_t)(gn>>9)<<24);  // +16M elems if K-half
          dst[(size_t)gm*512 + (gn&511)] = f2b(v);
        } else {
          ((u16b*)Cv)[(size_t)gm*N + gn] = f2b(v);
        }
      }
}

// ---------------------------------------------------------------------------
// Windowed attention per (window w, head h). 4 waves, 32 q-rows each.
// QT/KT: [32768][512] (s-major). V2: [512][32768] (e-major). GT aliases KT
// (block-private tile; all K reads precede the barrier, GT writes follow).
// ---------------------------------------------------------------------------
__global__ __launch_bounds__(256,2)
void attn_k(const u16b* __restrict__ QT, const u16b* __restrict__ KT,
            const u16b* __restrict__ V2, const u16b* __restrict__ mask,
            u16b* __restrict__ GT)
{
  __shared__ u16b v_sh[64][136];
  __shared__ u16b p_sh[4][32][136];
  const int bid = blockIdx.x;
  const int w = bid>>3, h = bid&7;
  const int tid = threadIdx.x, lane = tid&63, wv = tid>>6;
  const int q = lane>>4, ln = lane&15;
  const size_t cb = (size_t)w*128;

#pragma unroll
  for (int i=0;i<4;i++){
    int idx=i*256+tid, row=idx>>4, ch=(idx&15)*8;
    *(short8*)&v_sh[row][ch] =
        *(const short8*)&V2[(size_t)(h*64+row)*32768 + cb + ch];
  }

  short8 qf[2][2], kf[8][2];
#pragma unroll
  for (int mt=0;mt<2;mt++)
#pragma unroll
    for (int ks=0;ks<2;ks++)
      qf[mt][ks] = *(const short8*)&QT[(cb + wv*32 + mt*16 + ln)*512 + h*64 + ks*32 + q*8];
#pragma unroll
  for (int nt=0;nt<8;nt++)
#pragma unroll
    for (int ks=0;ks<2;ks++)
      kf[nt][ks] = *(const short8*)&KT[(cb + nt*16 + ln)*512 + h*64 + ks*32 + q*8];

  float4v sa[2][8];
#pragma unroll
  for (int mt=0;mt<2;mt++)
#pragma unroll
    for (int nt=0;nt<8;nt++) sa[mt][nt] = float4v{0.f,0.f,0.f,0.f};
#pragma unroll
  for (int ks=0;ks<2;ks++)
#pragma unroll
    for (int mt=0;mt<2;mt++)
#pragma unroll
      for (int nt=0;nt<8;nt++)
        sa[mt][nt] = __builtin_amdgcn_mfma_f32_16x16x32_bf16(
            qf[mt][ks], kf[nt][ks], sa[mt][nt], 0,0,0);

  float mk[8];
#pragma unroll
  for (int nt=0;nt<8;nt++) mk[nt] = b2f(mask[cb + nt*16 + ln]);
#pragma unroll
  for (int mt=0;mt<2;mt++)
#pragma unroll
    for (int nt=0;nt<8;nt++)
#pragma unroll
      for (int r=0;r<4;r++){
        float s = sa[mt][nt][r]*0.125f;          // /sqrt(dh=64)
        sa[mt][nt][r] = (mk[nt] > 0.0f) ? s : -1e9f;
      }

  float mrow[2][4], lrow[2][4];
#pragma unroll
  for (int mt=0;mt<2;mt++)
#pragma unroll
    for (int r=0;r<4;r++){
      float m = -3e38f;
#pragma unroll
      for (int nt=0;nt<8;nt++) m = fmaxf(m, sa[mt][nt][r]);
#pragma unroll
      for (int d=1; d<16; d<<=1) m = fmaxf(m, __shfl_xor(m, d));
      mrow[mt][r] = m;
    }
#pragma unroll
  for (int mt=0;mt<2;mt++)
#pragma unroll
    for (int nt=0;nt<8;nt++)
#pragma unroll
      for (int r=0;r<4;r++)
        sa[mt][nt][r] = __expf(sa[mt][nt][r] - mrow[mt][r]);
#pragma unroll
  for (int mt=0;mt<2;mt++)
#pragma unroll
    for (int r=0;r<4;r++){
      float l = 0.f;
#pragma unroll
      for (int nt=0;nt<8;nt++) l += sa[mt][nt][r];
#pragma unroll
      for (int d=1; d<16; d<<=1) l += __shfl_xor(l, d);
      lrow[mt][r] = l;
    }

#pragma unroll
  for (int mt=0;mt<2;mt++)
#pragma unroll
    for (int nt=0;nt<8;nt++)
#pragma unroll
      for (int r=0;r<4;r++)
        p_sh[wv][mt*16 + q*4 + r][nt*16 + ln] = f2b(sa[mt][nt][r]);
  __syncthreads();   // covers v_sh staging, p_sh, and all KT(GT-alias) reads

  float4v oa[2][4];
#pragma unroll
  for (int mt=0;mt<2;mt++)
#pragma unroll
    for (int nt=0;nt<4;nt++) oa[mt][nt] = float4v{0.f,0.f,0.f,0.f};
#pragma unroll
  for (int ks=0;ks<4;ks++){
    short8 pf[2], vf[4];
#pragma unroll
    for (int mt=0;mt<2;mt++) pf[mt] = *(const short8*)&p_sh[wv][mt*16+ln][ks*32+q*8];
#pragma unroll
    for (int nt=0;nt<4;nt++) vf[nt] = *(const short8*)&v_sh[nt*16+ln][ks*32+q*8];
#pragma unroll
    for (int mt=0;mt<2;mt++)
#pragma unroll
      for (int nt=0;nt<4;nt++)
        oa[mt][nt] = __builtin_amdgcn_mfma_f32_16x16x32_bf16(
            pf[mt], vf[nt], oa[mt][nt], 0,0,0);
  }

#pragma unroll
  for (int mt=0;mt<2;mt++)
#pragma unroll
    for (int nt=0;nt<4;nt++)
#pragma unroll
      for (int r=0;r<4;r++){
        float x = oa[mt][nt][r] * (1.0f / lrow[mt][r]);
        float g = 0.5f * x * (1.0f + erff(x * 0.70710678118f));
        GT[(cb + wv*32 + mt*16 + q*4 + r)*512 + h*64 + nt*16 + ln] = f2b(g);
      }
}

// ---------------------------------------------------------------------------
extern "C" void kernel_launch(void* const* d_in, const int* in_sizes, int n_in,
                              void* d_out, int out_size, void* d_ws, size_t ws_size,
                              hipStream_t stream)
{
  const void* qk    = d_in[0];
  const void* v     = d_in[1];
  const void* masks = d_in[2];

  char* ws = (char*)d_ws;
  int*  flag  = (int*)ws;                          // [0,1KB)
  u16b* wbase = (u16b*)(ws + 1024);                // canonical bf16 weights
  const int OWQ=0, OWK=524288, OWV=1048576, OWO=1572864;
  const int OBQ=2097152, OBK=2097664, OBV=2098176, OBO=2098688, OMSK=2099712;

  u16b* QT  = (u16b*)(ws + ((size_t)  8<<20));     // [32768][512] 32MB
  u16b* KT  = (u16b*)(ws + ((size_t) 40<<20));     // [32768][512] 32MB (=QT+16M)
  u16b* V2  = (u16b*)(ws + ((size_t) 72<<20));     // [512][32768] 32MB
  u16b* Xtq = (u16b*)(ws + ((size_t)104<<20));     // [32768][1024] 64MB
  u16b* Xtv = (u16b*)(ws + ((size_t)168<<20));     // [32768][1024] 64MB
  u16b* GT  = KT;

  sniff_k<<<1,256,0,stream>>>(qk, flag);

  IngestArgs ia;
  ia.src[0]=d_in[3]; ia.n[0]=524288; ia.off[0]=OWQ;   // Wq
  ia.src[1]=d_in[5]; ia.n[1]=524288; ia.off[1]=OWK;   // Wk
  ia.src[2]=d_in[7]; ia.n[2]=524288; ia.off[2]=OWV;   // Wv
  ia.src[3]=d_in[9]; ia.n[3]=524288; ia.off[3]=OWO;   // Wo
  ia.src[4]=d_in[4]; ia.n[4]=512;    ia.off[4]=OBQ;   // bq
  ia.src[5]=d_in[6]; ia.n[5]=512;    ia.off[5]=OBK;   // bk  (adjacent to bq)
  ia.src[6]=d_in[8]; ia.n[6]=512;    ia.off[6]=OBV;   // bv
  ia.src[7]=d_in[10];ia.n[7]=1024;   ia.off[7]=OBO;   // bo
  ia.src[8]=masks;   ia.n[8]=32768;  ia.off[8]=OMSK;  // masks
  ingest_k<<<1024,256,0,stream>>>(ia, wbase, flag);

  transpose2_k<<<dim3(64,16,16),256,0,stream>>>(qk, v, Xtq, Xtv, flag);
  // fused Q+K projection: B rows = [Wq ; Wk] (contiguous in wbase)
  gemm_kt<3><<<dim3(8,256),256,0,stream>>>(Xtq, wbase+OWQ, QT, wbase+OBQ, nullptr, flag, 32768, 1024, 1024);
  gemm_kt<1><<<dim3(256,4),256,0,stream>>>(wbase+OWV, Xtv, V2, wbase+OBV, nullptr, flag, 512, 32768, 1024);
  attn_k<<<2048,256,0,stream>>>(QT, KT, V2, wbase+OMSK, GT);
  gemm_kt<2><<<dim3(256,8),256,0,stream>>>(wbase+OWO, GT, d_out, wbase+OBO, wbase+OMSK, flag, 1024, 32768, 512);
}